// Round 3
// baseline (53525.208 us; speedup 1.0000x reference)
//
#include <hip/hip_runtime.h>

// SentimentNet on MI355X — round 3: fenceless LLC barrier + backoff + split
// signal line.
//
// Round-2 post-mortem: tight sc1 poll loop with no backoff flooded the
// fabric/LLC (74 GB fetch, 78 GB write) and the pollers contended with the
// arrive fetch_adds on the same line -> barrier latency ballooned.
// Round 3: pollers read a dedicated per-team epoch word (written once per
// step by the last arriver) with s_sleep(1) backoff; fetch_adds live on a
// separate cache line. All atomics remain relaxed/agent (no wbl2/inv).

#define S_LEN 500
#define BATCH 64
#define EDIM 512
#define HDIM 512
#define TEAMS 8
#define WGS_PER_TEAM 32
#define TB 8                      // batches per team
#define NBLOCKS (TEAMS * WGS_PER_TEAM)
#define NTHREADS 512

// workspace layout (bytes)
#define STATES_BYTES (S_LEN * BATCH * HDIM * 4)        // 65,536,000
#define HBUF_OFF     STATES_BYTES
#define HBUF_BYTES   (2 * TEAMS * TB * HDIM * 4)       // 262,144
#define PART_OFF     (HBUF_OFF + HBUF_BYTES)           // 65,798,144
#define PART_BYTES   (4 * S_LEN * BATCH * 4)           // 512,000
#define BAR_OFF      (PART_OFF + PART_BYTES)           // 66,310,144
#define BAR_BYTES    4096

__global__ __launch_bounds__(NTHREADS, 2) void lstm_persistent(
    const int* __restrict__ idx, const float* __restrict__ emb,
    const float* __restrict__ W_ih, const float* __restrict__ W_hh,
    const float* __restrict__ b_ih, const float* __restrict__ b_hh,
    float* __restrict__ states, float* __restrict__ h_buf, int* bar) {
  __shared__ float embL[8][TB][64];   // [wave][batch][k-chunk]
  __shared__ float hL[8][TB][64];
  __shared__ float red[8][TB][64];    // [wave][batch][row]
  __shared__ float zL[TB][64];        // [batch][row]

  const int team = blockIdx.x >> 5;          // 0..7
  const int wg   = blockIdx.x & 31;          // 0..31 -> units [16wg,16wg+16)
  const int tid  = threadIdx.x;
  const int w    = tid >> 6;                 // wave 0..7 -> k chunk [64w,64w+64)
  const int l    = tid & 63;                 // lane -> row within WG

  int* cnt = bar + team * 64;                // RMW line   (256B per team)
  int* ep  = bar + team * 64 + 32;           // signal line (128B away)

  // gate-row for (wg, lane): row r -> g = 16*wg + (r&15) + 512*(r>>4)
  const int g = 16 * wg + (l & 15) + 512 * (l >> 4);

  // register-stationary weights: this lane's row, this wave's 64-k chunk
  float wih[64], whh[64];
  {
    const float4* pih = (const float4*)(W_ih + (size_t)g * EDIM + (size_t)w * 64);
    const float4* phh = (const float4*)(W_hh + (size_t)g * HDIM + (size_t)w * 64);
#pragma unroll
    for (int j = 0; j < 16; ++j) {
      float4 v = pih[j];
      wih[4 * j + 0] = v.x; wih[4 * j + 1] = v.y; wih[4 * j + 2] = v.z; wih[4 * j + 3] = v.w;
    }
#pragma unroll
    for (int j = 0; j < 16; ++j) {
      float4 v = phh[j];
      whh[4 * j + 0] = v.x; whh[4 * j + 1] = v.y; whh[4 * j + 2] = v.z; whh[4 * j + 3] = v.w;
    }
  }

  // reduce-thread identity: (rr=row, rb=batch)
  const int rr = tid & 63, rb = tid >> 6;
  const int gr = 16 * wg + (rr & 15) + 512 * (rr >> 4);
  const float bias = b_ih[gr] + b_hh[gr];

  // gate-thread identity (tid<128): unit gu, batch gb
  const int gu = tid & 15, gb = tid >> 4;
  float c_state = 0.f;

  // prefetch embedding for s=0: lane l reads element (64w+l) of each batch row
  float ereg[TB];
#pragma unroll
  for (int b = 0; b < TB; ++b) {
    int row = idx[0 * BATCH + team * TB + b];
    ereg[b] = emb[(size_t)row * EDIM + (size_t)w * 64 + l];
  }

  for (int s = 0; s < S_LEN; ++s) {
    // stage current embed chunk (own-wave region only)
#pragma unroll
    for (int b = 0; b < TB; ++b) embL[w][b][l] = ereg[b];

    // x-projection dot (independent of h(s-1)) — fills the barrier slack
    float acc[TB];
#pragma unroll
    for (int b = 0; b < TB; ++b) {
      float a = 0.f;
      const float4* eb = (const float4*)&embL[w][b][0];
#pragma unroll
      for (int k4 = 0; k4 < 16; ++k4) {
        float4 e = eb[k4];
        a = fmaf(wih[4 * k4 + 0], e.x, a);
        a = fmaf(wih[4 * k4 + 1], e.y, a);
        a = fmaf(wih[4 * k4 + 2], e.z, a);
        a = fmaf(wih[4 * k4 + 3], e.w, a);
      }
      acc[b] = a;
    }

    // issue embed prefetch for s+1 (in flight across the wait)
    if (s + 1 < S_LEN) {
#pragma unroll
      for (int b = 0; b < TB; ++b) {
        int row = idx[(s + 1) * BATCH + team * TB + b];
        ereg[b] = emb[(size_t)row * EDIM + (size_t)w * 64 + l];
      }
    }

    if (s > 0) {
      // wait: epoch word (written once/step by last arriver), sleep backoff
      if (tid == 0) {
        int spins = 0;
        while (__hip_atomic_load(ep, __ATOMIC_RELAXED, __HIP_MEMORY_SCOPE_AGENT) < s) {
          __builtin_amdgcn_s_sleep(1);
          if (++spins > (1 << 22)) break;    // bounded: never hang
        }
      }
      __syncthreads();
      // load h(s-1) from LLC: layout [par][team][b][unit] -> coalesced
      const int par = s & 1;
      float hl[TB];
#pragma unroll
      for (int b = 0; b < TB; ++b)
        hl[b] = __hip_atomic_load(
            &h_buf[(((size_t)par * TEAMS + team) * TB + b) * HDIM + (w * 64 + l)],
            __ATOMIC_RELAXED, __HIP_MEMORY_SCOPE_AGENT);
#pragma unroll
      for (int b = 0; b < TB; ++b) hL[w][b][l] = hl[b];
      // recurrent dot
#pragma unroll
      for (int b = 0; b < TB; ++b) {
        float a = acc[b];
        const float4* hb = (const float4*)&hL[w][b][0];
#pragma unroll
        for (int k4 = 0; k4 < 16; ++k4) {
          float4 h4 = hb[k4];
          a = fmaf(whh[4 * k4 + 0], h4.x, a);
          a = fmaf(whh[4 * k4 + 1], h4.y, a);
          a = fmaf(whh[4 * k4 + 2], h4.z, a);
          a = fmaf(whh[4 * k4 + 3], h4.w, a);
        }
        acc[b] = a;
      }
    }

    // k-reduce across the 8 waves
#pragma unroll
    for (int b = 0; b < TB; ++b) red[w][b][l] = acc[b];
    __syncthreads();
    {
      float z = bias;
#pragma unroll
      for (int w2 = 0; w2 < 8; ++w2) z += red[w2][rb][rr];
      zL[rb][rr] = z;
    }
    __syncthreads();

    // gates: thread t<128 owns (unit gu, batch gb)
    if (tid < 128) {
      float zi = zL[gb][gu +  0];
      float zf = zL[gb][gu + 16];
      float zg = zL[gb][gu + 32];
      float zo = zL[gb][gu + 48];
      float i_ = 1.f / (1.f + expf(-zi));
      float f_ = 1.f / (1.f + expf(-zf));
      float o_ = 1.f / (1.f + expf(-zo));
      float g_ = tanhf(zg);
      c_state = f_ * c_state + i_ * g_;
      float h_ = o_ * tanhf(c_state);
      int unit = 16 * wg + gu;
      __hip_atomic_store(
          &h_buf[(((size_t)((s + 1) & 1) * TEAMS + team) * TB + gb) * HDIM + unit],
          h_, __ATOMIC_RELAXED, __HIP_MEMORY_SCOPE_AGENT);
      states[((size_t)s * BATCH + team * TB + gb) * HDIM + unit] = h_;
    }

    // arrive: __syncthreads drains vmcnt (h stores at LLC), then count; the
    // last arriver publishes the epoch on a separate line.
    __syncthreads();
    if (tid == 0 && s + 1 < S_LEN) {
      int prev = __hip_atomic_fetch_add(cnt, 1, __ATOMIC_RELAXED, __HIP_MEMORY_SCOPE_AGENT);
      if (prev == WGS_PER_TEAM * (s + 1) - 1)
        __hip_atomic_store(ep, s + 1, __ATOMIC_RELAXED, __HIP_MEMORY_SCOPE_AGENT);
    }
  }
}

// ---------------- attention GEMM: tanh(states@W_word + b_word) @ w_proj ----------------
#define ATP 132
__global__ __launch_bounds__(256) void attn_gemm(
    const float* __restrict__ states, const float* __restrict__ W_word,
    const float* __restrict__ b_word, const float* __restrict__ w_proj,
    float* __restrict__ part) {
  __shared__ float At[16][ATP];   // A transposed tile [k][m]
  __shared__ float Bt[16][ATP];   // B tile [k][n]
  __shared__ float redl[128][17];

  const int tid = threadIdx.x;
  const int m0 = blockIdx.x * 128;   // token tile
  const int n0 = blockIdx.y * 128;   // tanh-dim tile
  const int ty = tid >> 4, tx = tid & 15;

  float acc[8][8];
#pragma unroll
  for (int i = 0; i < 8; ++i)
#pragma unroll
    for (int j = 0; j < 8; ++j) acc[i][j] = 0.f;

  for (int k0 = 0; k0 < 512; k0 += 16) {
#pragma unroll
    for (int it = 0; it < 2; ++it) {
      int m = (tid >> 2) + 64 * it;
      int kq = tid & 3;
      float4 v = *(const float4*)&states[(size_t)(m0 + m) * 512 + k0 + 4 * kq];
      At[4 * kq + 0][m] = v.x; At[4 * kq + 1][m] = v.y;
      At[4 * kq + 2][m] = v.z; At[4 * kq + 3][m] = v.w;
    }
#pragma unroll
    for (int it = 0; it < 2; ++it) {
      int kr = (tid >> 5) + 8 * it;
      int nq = tid & 31;
      float4 v = *(const float4*)&W_word[(size_t)(k0 + kr) * 512 + n0 + 4 * nq];
      *(float4*)&Bt[kr][4 * nq] = v;
    }
    __syncthreads();
#pragma unroll
    for (int kk = 0; kk < 16; ++kk) {
      float4 a0 = *(const float4*)&At[kk][ty * 8];
      float4 a1 = *(const float4*)&At[kk][ty * 8 + 4];
      float4 b0 = *(const float4*)&Bt[kk][tx * 8];
      float4 b1 = *(const float4*)&Bt[kk][tx * 8 + 4];
      float av[8] = {a0.x, a0.y, a0.z, a0.w, a1.x, a1.y, a1.z, a1.w};
      float bv[8] = {b0.x, b0.y, b0.z, b0.w, b1.x, b1.y, b1.z, b1.w};
#pragma unroll
      for (int i = 0; i < 8; ++i)
#pragma unroll
        for (int j = 0; j < 8; ++j) acc[i][j] = fmaf(av[i], bv[j], acc[i][j]);
    }
    __syncthreads();
  }
  // epilogue: tanh(acc + b_word[n]) * w_proj[n], reduce over this block's 128 n-cols
  float bw[8], wp[8];
  {
    float4 v0 = *(const float4*)&b_word[n0 + tx * 8];
    float4 v1 = *(const float4*)&b_word[n0 + tx * 8 + 4];
    bw[0]=v0.x; bw[1]=v0.y; bw[2]=v0.z; bw[3]=v0.w; bw[4]=v1.x; bw[5]=v1.y; bw[6]=v1.z; bw[7]=v1.w;
    float4 u0 = *(const float4*)&w_proj[n0 + tx * 8];
    float4 u1 = *(const float4*)&w_proj[n0 + tx * 8 + 4];
    wp[0]=u0.x; wp[1]=u0.y; wp[2]=u0.z; wp[3]=u0.w; wp[4]=u1.x; wp[5]=u1.y; wp[6]=u1.z; wp[7]=u1.w;
  }
#pragma unroll
  for (int i = 0; i < 8; ++i) {
    float rs = 0.f;
#pragma unroll
    for (int j = 0; j < 8; ++j) rs += tanhf(acc[i][j] + bw[j]) * wp[j];
    redl[ty * 8 + i][tx] = rs;
  }
  __syncthreads();
  if (tid < 128) {
    float ssum = 0.f;
#pragma unroll
    for (int x = 0; x < 16; ++x) ssum += redl[tid][x];
    part[(size_t)blockIdx.y * (S_LEN * BATCH) + m0 + tid] = ssum;
  }
}

// ---------------- softmax over S + pooled sum + decode ----------------
__global__ __launch_bounds__(256) void softmax_pool_decode(
    const float* __restrict__ part, const float* __restrict__ states,
    const float* __restrict__ dec_W, const float* __restrict__ dec_b,
    float* __restrict__ out) {
  const int b = blockIdx.x;
  const int tid = threadIdx.x;
  __shared__ float sc[S_LEN];
  __shared__ float pool[HDIM];
  __shared__ float redm[256];

  for (int s = tid; s < S_LEN; s += 256) {
    int t = s * BATCH + b;
    sc[s] = part[t] + part[S_LEN * BATCH + t] + part[2 * S_LEN * BATCH + t] +
            part[3 * S_LEN * BATCH + t];
  }
  __syncthreads();
  float m = -1e30f;
  for (int s = tid; s < S_LEN; s += 256) m = fmaxf(m, sc[s]);
  redm[tid] = m; __syncthreads();
  for (int o = 128; o > 0; o >>= 1) {
    if (tid < o) redm[tid] = fmaxf(redm[tid], redm[tid + o]);
    __syncthreads();
  }
  const float gmax = redm[0];
  __syncthreads();
  float lsum = 0.f;
  for (int s = tid; s < S_LEN; s += 256) { float e = expf(sc[s] - gmax); sc[s] = e; lsum += e; }
  redm[tid] = lsum; __syncthreads();
  for (int o = 128; o > 0; o >>= 1) {
    if (tid < o) redm[tid] += redm[tid + o];
    __syncthreads();
  }
  const float inv = 1.f / redm[0];
  __syncthreads();
  for (int h = tid; h < HDIM; h += 256) {
    float a = 0.f;
    for (int s = 0; s < S_LEN; ++s)
      a = fmaf(sc[s], states[((size_t)s * BATCH + b) * HDIM + h], a);
    pool[h] = a * inv;
  }
  __syncthreads();
  // decode: 2 halves of 128 threads, each sums 4 h-elems then tree-reduce
  const int lcls = tid >> 7, ch = tid & 127;
  float p = 0.f;
#pragma unroll
  for (int j = 0; j < 4; ++j)
    p = fmaf(pool[ch * 4 + j], dec_W[lcls * HDIM + ch * 4 + j], p);
  redm[tid] = p; __syncthreads();
  for (int o = 64; o > 0; o >>= 1) {
    if (ch < o) redm[tid] += redm[tid + o];
    __syncthreads();
  }
  if (ch == 0) out[b * 2 + lcls] = redm[tid] + dec_b[lcls];
}

extern "C" void kernel_launch(void* const* d_in, const int* in_sizes, int n_in,
                              void* d_out, int out_size, void* d_ws, size_t ws_size,
                              hipStream_t stream) {
  const int*   idx    = (const int*)d_in[0];
  // d_in[1] = text_lengths: unused by the reference
  const float* emb    = (const float*)d_in[2];
  const float* W_ih   = (const float*)d_in[3];
  const float* W_hh   = (const float*)d_in[4];
  const float* b_ih   = (const float*)d_in[5];
  const float* b_hh   = (const float*)d_in[6];
  const float* W_word = (const float*)d_in[7];
  const float* b_word = (const float*)d_in[8];
  const float* w_proj = (const float*)d_in[9];
  const float* dec_W  = (const float*)d_in[10];
  const float* dec_b  = (const float*)d_in[11];
  float* out = (float*)d_out;

  char* ws = (char*)d_ws;
  float* states = (float*)ws;
  float* h_buf  = (float*)(ws + HBUF_OFF);
  float* part   = (float*)(ws + PART_OFF);
  int*   bar    = (int*)(ws + BAR_OFF);

  // barrier counters must start at 0 every launch (monotonic within a launch)
  hipMemsetAsync(bar, 0, BAR_BYTES, stream);

  void* args[] = {(void*)&idx, (void*)&emb, (void*)&W_ih, (void*)&W_hh,
                  (void*)&b_ih, (void*)&b_hh, (void*)&states, (void*)&h_buf,
                  (void*)&bar};
  hipLaunchCooperativeKernel(lstm_persistent, dim3(NBLOCKS), dim3(NTHREADS), args, 0, stream);

  attn_gemm<<<dim3(250, 4), 256, 0, stream>>>(states, W_word, b_word, w_proj, part);
  softmax_pool_decode<<<64, 256, 0, stream>>>(part, states, dec_W, dec_b, out);
}

// Round 4
// 4450.251 us; speedup vs baseline: 12.0275x; 12.0275x over previous
//
#include <hip/hip_runtime.h>

// SentimentNet on MI355X — round 4: kill the register spill.
//
// Round-2/3 post-mortem: FETCH/WRITE byte-identical across rounds (74/78 GB)
// -> deterministic traffic = scratch spills. VGPR_Count=128 but ~170 live
// floats (wih[64]+whh[64]+...) -> compiler spilled the weight arrays; each
// step re-read+wrote them from scratch (~33.5 GB each way). Fix: hoist the
// x-projection to a separate parallel GEMM over all 500 steps (xproj in ws),
// so the persistent kernel holds only whh[64] per lane (no spill).
// Barrier: per-WG flag array (no RMW serialization), relaxed agent atomics
// only (no wbl2/inv), s_sleep backoff.

#define S_LEN 500
#define BATCH 64
#define EDIM 512
#define HDIM 512
#define TEAMS 8
#define WGS_PER_TEAM 32
#define TB 8                      // batches per team
#define NBLOCKS (TEAMS * WGS_PER_TEAM)
#define NTHREADS 512

// workspace layout (bytes)
#define XPROJ_BYTES  ((size_t)S_LEN * 2048 * BATCH * 4)   // 262,144,000
#define STATES_OFF   XPROJ_BYTES
#define STATES_BYTES ((size_t)S_LEN * BATCH * HDIM * 4)   // 65,536,000
#define HBUF_OFF     (STATES_OFF + STATES_BYTES)
#define HBUF_BYTES   (2 * TEAMS * TB * HDIM * 4)          // 262,144
#define PART_OFF     (HBUF_OFF + HBUF_BYTES)
#define PART_BYTES   (4 * S_LEN * BATCH * 4)              // 512,000
#define BAR_OFF      (PART_OFF + PART_BYTES)
#define BAR_BYTES    4096

// ---------------- xproj GEMM: xproj[s][g][b] = W_ih[g,:]·emb[idx[s,b],:] + b_ih[g]+b_hh[g]
__global__ __launch_bounds__(256) void xproj_gemm(
    const int* __restrict__ idx, const float* __restrict__ emb,
    const float* __restrict__ W_ih, const float* __restrict__ b_ih,
    const float* __restrict__ b_hh, float* __restrict__ xproj) {
  __shared__ float At[16][132];   // [k][g]
  __shared__ float Bt[16][132];   // [k][sb]
  __shared__ int sidx[128];

  const int tid = threadIdx.x;
  const int sb0 = blockIdx.x * 128;   // (s,b) flat tile
  const int g0  = blockIdx.y * 128;   // gate-row tile
  if (tid < 128) sidx[tid] = idx[sb0 + tid];

  const int ty = tid >> 4, tx = tid & 15;
  const int ra = tid & 127, pp = tid >> 7;   // row/col within tile, 8-k part

  float acc[8][8];
#pragma unroll
  for (int i = 0; i < 8; ++i)
#pragma unroll
    for (int j = 0; j < 8; ++j) acc[i][j] = 0.f;

  __syncthreads();   // sidx ready

  for (int k0 = 0; k0 < 512; k0 += 16) {
    const float* pa = &W_ih[(size_t)(g0 + ra) * 512 + k0 + 8 * pp];
    float4 a0 = *(const float4*)pa, a1 = *(const float4*)(pa + 4);
    const float* pb = &emb[(size_t)sidx[ra] * 512 + k0 + 8 * pp];
    float4 b0 = *(const float4*)pb, b1 = *(const float4*)(pb + 4);
    At[8*pp+0][ra]=a0.x; At[8*pp+1][ra]=a0.y; At[8*pp+2][ra]=a0.z; At[8*pp+3][ra]=a0.w;
    At[8*pp+4][ra]=a1.x; At[8*pp+5][ra]=a1.y; At[8*pp+6][ra]=a1.z; At[8*pp+7][ra]=a1.w;
    Bt[8*pp+0][ra]=b0.x; Bt[8*pp+1][ra]=b0.y; Bt[8*pp+2][ra]=b0.z; Bt[8*pp+3][ra]=b0.w;
    Bt[8*pp+4][ra]=b1.x; Bt[8*pp+5][ra]=b1.y; Bt[8*pp+6][ra]=b1.z; Bt[8*pp+7][ra]=b1.w;
    __syncthreads();
#pragma unroll
    for (int kk = 0; kk < 16; ++kk) {
      float4 x0 = *(const float4*)&At[kk][ty * 8];
      float4 x1 = *(const float4*)&At[kk][ty * 8 + 4];
      float4 y0 = *(const float4*)&Bt[kk][tx * 8];
      float4 y1 = *(const float4*)&Bt[kk][tx * 8 + 4];
      float av[8] = {x0.x, x0.y, x0.z, x0.w, x1.x, x1.y, x1.z, x1.w};
      float bv[8] = {y0.x, y0.y, y0.z, y0.w, y1.x, y1.y, y1.z, y1.w};
#pragma unroll
      for (int i = 0; i < 8; ++i)
#pragma unroll
        for (int j = 0; j < 8; ++j) acc[i][j] = fmaf(av[i], bv[j], acc[i][j]);
    }
    __syncthreads();
  }
  // epilogue: + (b_ih+b_hh), store to xproj[s][g][b]
#pragma unroll
  for (int i = 0; i < 8; ++i) {
    const int g = g0 + ty * 8 + i;
    const float bias = b_ih[g] + b_hh[g];
#pragma unroll
    for (int j2 = 0; j2 < 8; j2 += 4) {
      const int sb = sb0 + tx * 8 + j2;
      const int s = sb >> 6, b = sb & 63;
      float4 v = {acc[i][j2] + bias, acc[i][j2+1] + bias,
                  acc[i][j2+2] + bias, acc[i][j2+3] + bias};
      *(float4*)&xproj[((size_t)s * 2048 + g) * 64 + b] = v;
    }
  }
}

// ---------------- persistent recurrence ----------------
__global__ __launch_bounds__(NTHREADS, 2) void lstm_persistent(
    const float* __restrict__ xproj, const float* __restrict__ W_hh,
    float* __restrict__ states, float* __restrict__ h_buf, int* bar) {
  __shared__ float hL[8][TB][64];     // [wave][batch][k-chunk]
  __shared__ float red[8][TB][64];    // [wave][batch][row]
  __shared__ float zL[TB][65];        // [batch][row] (padded)
  __shared__ float xpL[64][9];        // [row][batch] (padded)

  const int team = blockIdx.x >> 5;          // 0..7
  const int wg   = blockIdx.x & 31;          // 0..31 -> units [16wg,16wg+16)
  const int tid  = threadIdx.x;
  const int w    = tid >> 6;                 // wave 0..7 -> k chunk [64w,64w+64)
  const int l    = tid & 63;                 // lane -> row within WG

  int* flags = bar + team * 64;              // 32 ints (one per WG), 256B/team

  // gate-row for (wg, lane): row r -> g = 16*wg + (r&15) + 512*(r>>4)
  const int g = 16 * wg + (l & 15) + 512 * (l >> 4);

  // register-stationary recurrent weights: this lane's row, this wave's k-chunk
  float whh[64];
  {
    const float4* phh = (const float4*)(W_hh + (size_t)g * HDIM + (size_t)w * 64);
#pragma unroll
    for (int j = 0; j < 16; ++j) {
      float4 v = phh[j];
      whh[4*j+0] = v.x; whh[4*j+1] = v.y; whh[4*j+2] = v.z; whh[4*j+3] = v.w;
    }
  }

  // xv-prefetch identity: thread -> (row r, batch bb); covers 64 rows x 8 b
  const int r = tid >> 3, bb = tid & 7;
  const int gx = 16 * wg + (r & 15) + 512 * (r >> 4);
  const size_t xbase = ((size_t)gx) * 64 + team * 8 + bb;

  // reduce-thread identity: (rr=row, rb=batch)
  const int rr = tid & 63, rb = tid >> 6;

  // gate-thread identity (tid<128): unit gu, batch gb
  const int gu = tid & 15, gb = tid >> 4;
  float c_state = 0.f;

  for (int s = 0; s < S_LEN; ++s) {
    // issue xproj[s] load early (consumed after the dot)
    const float xv = xproj[(size_t)s * 2048 * 64 + xbase];

    float acc[TB];
#pragma unroll
    for (int b = 0; b < TB; ++b) acc[b] = 0.f;

    if (s > 0) {
      // wait: all 32 team flags >= s (wave 0 scans them coalesced)
      if (tid < 64) {
        const int lane = tid & 31;
        int spins = 0;
        for (;;) {
          int v = __hip_atomic_load(flags + lane, __ATOMIC_RELAXED,
                                    __HIP_MEMORY_SCOPE_AGENT);
          if (__all(v >= s)) break;
          __builtin_amdgcn_s_sleep(1);
          if (++spins > (1 << 22)) break;    // hang guard only
        }
      }
      __syncthreads();
      // load h(s-1) from LLC: [par][team][b][unit], coalesced per wave
      const int par = s & 1;
      float hl[TB];
#pragma unroll
      for (int b = 0; b < TB; ++b)
        hl[b] = __hip_atomic_load(
            &h_buf[(((size_t)par * TEAMS + team) * TB + b) * HDIM + (w * 64 + l)],
            __ATOMIC_RELAXED, __HIP_MEMORY_SCOPE_AGENT);
#pragma unroll
      for (int b = 0; b < TB; ++b) hL[w][b][l] = hl[b];
      // recurrent dot: this wave's 64-k chunk (LDS reads are broadcasts)
#pragma unroll
      for (int b = 0; b < TB; ++b) {
        float a = acc[b];
        const float4* hb = (const float4*)&hL[w][b][0];
#pragma unroll
        for (int k4 = 0; k4 < 16; ++k4) {
          float4 h4 = hb[k4];
          a = fmaf(whh[4*k4+0], h4.x, a);
          a = fmaf(whh[4*k4+1], h4.y, a);
          a = fmaf(whh[4*k4+2], h4.z, a);
          a = fmaf(whh[4*k4+3], h4.w, a);
        }
        acc[b] = a;
      }
    }

    // publish partials + xv, reduce across waves
#pragma unroll
    for (int b = 0; b < TB; ++b) red[w][b][l] = acc[b];
    xpL[r][bb] = xv;
    __syncthreads();
    {
      float z = 0.f;
#pragma unroll
      for (int w2 = 0; w2 < 8; ++w2) z += red[w2][rb][rr];
      zL[rb][rr] = z;
    }
    __syncthreads();

    // gates: thread t<128 owns (unit gu, batch gb)
    if (tid < 128) {
      float zi = zL[gb][gu +  0] + xpL[gu +  0][gb];
      float zf = zL[gb][gu + 16] + xpL[gu + 16][gb];
      float zg = zL[gb][gu + 32] + xpL[gu + 32][gb];
      float zo = zL[gb][gu + 48] + xpL[gu + 48][gb];
      float i_ = 1.f / (1.f + expf(-zi));
      float f_ = 1.f / (1.f + expf(-zf));
      float o_ = 1.f / (1.f + expf(-zo));
      float g_ = tanhf(zg);
      c_state = f_ * c_state + i_ * g_;
      float h_ = o_ * tanhf(c_state);
      const int unit = 16 * wg + gu;
      __hip_atomic_store(
          &h_buf[(((size_t)((s + 1) & 1) * TEAMS + team) * TB + gb) * HDIM + unit],
          h_, __ATOMIC_RELAXED, __HIP_MEMORY_SCOPE_AGENT);
      states[((size_t)s * BATCH + team * TB + gb) * HDIM + unit] = h_;  // plain store
    }

    // arrive: __syncthreads drains vmcnt (h stores at LLC), then own-flag store
    __syncthreads();
    if (tid == 0 && s + 1 < S_LEN)
      __hip_atomic_store(flags + wg, s + 1, __ATOMIC_RELAXED,
                         __HIP_MEMORY_SCOPE_AGENT);
  }
}

// ---------------- attention GEMM: tanh(states@W_word + b_word) @ w_proj ----------------
#define ATP 132
__global__ __launch_bounds__(256) void attn_gemm(
    const float* __restrict__ states, const float* __restrict__ W_word,
    const float* __restrict__ b_word, const float* __restrict__ w_proj,
    float* __restrict__ part) {
  __shared__ float At[16][ATP];   // A transposed tile [k][m]
  __shared__ float Bt[16][ATP];   // B tile [k][n]
  __shared__ float redl[128][17];

  const int tid = threadIdx.x;
  const int m0 = blockIdx.x * 128;   // token tile
  const int n0 = blockIdx.y * 128;   // tanh-dim tile
  const int ty = tid >> 4, tx = tid & 15;

  float acc[8][8];
#pragma unroll
  for (int i = 0; i < 8; ++i)
#pragma unroll
    for (int j = 0; j < 8; ++j) acc[i][j] = 0.f;

  for (int k0 = 0; k0 < 512; k0 += 16) {
#pragma unroll
    for (int it = 0; it < 2; ++it) {
      int m = (tid >> 2) + 64 * it;
      int kq = tid & 3;
      float4 v = *(const float4*)&states[(size_t)(m0 + m) * 512 + k0 + 4 * kq];
      At[4 * kq + 0][m] = v.x; At[4 * kq + 1][m] = v.y;
      At[4 * kq + 2][m] = v.z; At[4 * kq + 3][m] = v.w;
    }
#pragma unroll
    for (int it = 0; it < 2; ++it) {
      int kr = (tid >> 5) + 8 * it;
      int nq = tid & 31;
      float4 v = *(const float4*)&W_word[(size_t)(k0 + kr) * 512 + n0 + 4 * nq];
      *(float4*)&Bt[kr][4 * nq] = v;
    }
    __syncthreads();
#pragma unroll
    for (int kk = 0; kk < 16; ++kk) {
      float4 a0 = *(const float4*)&At[kk][ty * 8];
      float4 a1 = *(const float4*)&At[kk][ty * 8 + 4];
      float4 b0 = *(const float4*)&Bt[kk][tx * 8];
      float4 b1 = *(const float4*)&Bt[kk][tx * 8 + 4];
      float av[8] = {a0.x, a0.y, a0.z, a0.w, a1.x, a1.y, a1.z, a1.w};
      float bv[8] = {b0.x, b0.y, b0.z, b0.w, b1.x, b1.y, b1.z, b1.w};
#pragma unroll
      for (int i = 0; i < 8; ++i)
#pragma unroll
        for (int j = 0; j < 8; ++j) acc[i][j] = fmaf(av[i], bv[j], acc[i][j]);
    }
    __syncthreads();
  }
  float bw[8], wp[8];
  {
    float4 v0 = *(const float4*)&b_word[n0 + tx * 8];
    float4 v1 = *(const float4*)&b_word[n0 + tx * 8 + 4];
    bw[0]=v0.x; bw[1]=v0.y; bw[2]=v0.z; bw[3]=v0.w; bw[4]=v1.x; bw[5]=v1.y; bw[6]=v1.z; bw[7]=v1.w;
    float4 u0 = *(const float4*)&w_proj[n0 + tx * 8];
    float4 u1 = *(const float4*)&w_proj[n0 + tx * 8 + 4];
    wp[0]=u0.x; wp[1]=u0.y; wp[2]=u0.z; wp[3]=u0.w; wp[4]=u1.x; wp[5]=u1.y; wp[6]=u1.z; wp[7]=u1.w;
  }
#pragma unroll
  for (int i = 0; i < 8; ++i) {
    float rs = 0.f;
#pragma unroll
    for (int j = 0; j < 8; ++j) rs += tanhf(acc[i][j] + bw[j]) * wp[j];
    redl[ty * 8 + i][tx] = rs;
  }
  __syncthreads();
  if (tid < 128) {
    float ssum = 0.f;
#pragma unroll
    for (int x = 0; x < 16; ++x) ssum += redl[tid][x];
    part[(size_t)blockIdx.y * (S_LEN * BATCH) + m0 + tid] = ssum;
  }
}

// ---------------- softmax over S + pooled sum + decode ----------------
__global__ __launch_bounds__(256) void softmax_pool_decode(
    const float* __restrict__ part, const float* __restrict__ states,
    const float* __restrict__ dec_W, const float* __restrict__ dec_b,
    float* __restrict__ out) {
  const int b = blockIdx.x;
  const int tid = threadIdx.x;
  __shared__ float sc[S_LEN];
  __shared__ float pool[HDIM];
  __shared__ float redm[256];

  for (int s = tid; s < S_LEN; s += 256) {
    int t = s * BATCH + b;
    sc[s] = part[t] + part[S_LEN * BATCH + t] + part[2 * S_LEN * BATCH + t] +
            part[3 * S_LEN * BATCH + t];
  }
  __syncthreads();
  float m = -1e30f;
  for (int s = tid; s < S_LEN; s += 256) m = fmaxf(m, sc[s]);
  redm[tid] = m; __syncthreads();
  for (int o = 128; o > 0; o >>= 1) {
    if (tid < o) redm[tid] = fmaxf(redm[tid], redm[tid + o]);
    __syncthreads();
  }
  const float gmax = redm[0];
  __syncthreads();
  float lsum = 0.f;
  for (int s = tid; s < S_LEN; s += 256) { float e = expf(sc[s] - gmax); sc[s] = e; lsum += e; }
  redm[tid] = lsum; __syncthreads();
  for (int o = 128; o > 0; o >>= 1) {
    if (tid < o) redm[tid] += redm[tid + o];
    __syncthreads();
  }
  const float inv = 1.f / redm[0];
  __syncthreads();
  for (int h = tid; h < HDIM; h += 256) {
    float a = 0.f;
    for (int s = 0; s < S_LEN; ++s)
      a = fmaf(sc[s], states[((size_t)s * BATCH + b) * HDIM + h], a);
    pool[h] = a * inv;
  }
  __syncthreads();
  const int lcls = tid >> 7, ch = tid & 127;
  float p = 0.f;
#pragma unroll
  for (int j = 0; j < 4; ++j)
    p = fmaf(pool[ch * 4 + j], dec_W[lcls * HDIM + ch * 4 + j], p);
  redm[tid] = p; __syncthreads();
  for (int o = 64; o > 0; o >>= 1) {
    if (ch < o) redm[tid] += redm[tid + o];
    __syncthreads();
  }
  if (ch == 0) out[b * 2 + lcls] = redm[tid] + dec_b[lcls];
}

extern "C" void kernel_launch(void* const* d_in, const int* in_sizes, int n_in,
                              void* d_out, int out_size, void* d_ws, size_t ws_size,
                              hipStream_t stream) {
  const int*   idx    = (const int*)d_in[0];
  // d_in[1] = text_lengths: unused by the reference
  const float* emb    = (const float*)d_in[2];
  const float* W_ih   = (const float*)d_in[3];
  const float* W_hh   = (const float*)d_in[4];
  const float* b_ih   = (const float*)d_in[5];
  const float* b_hh   = (const float*)d_in[6];
  const float* W_word = (const float*)d_in[7];
  const float* b_word = (const float*)d_in[8];
  const float* w_proj = (const float*)d_in[9];
  const float* dec_W  = (const float*)d_in[10];
  const float* dec_b  = (const float*)d_in[11];
  float* out = (float*)d_out;

  char* ws = (char*)d_ws;
  float* xproj  = (float*)ws;
  float* states = (float*)(ws + STATES_OFF);
  float* h_buf  = (float*)(ws + HBUF_OFF);
  float* part   = (float*)(ws + PART_OFF);
  int*   bar    = (int*)(ws + BAR_OFF);

  // flags must start at 0 every launch (monotonic within a launch)
  hipMemsetAsync(bar, 0, BAR_BYTES, stream);

  // 1) x-projection for all timesteps (parallel GEMM, 67 GFLOP)
  xproj_gemm<<<dim3(250, 16), 256, 0, stream>>>(idx, emb, W_ih, b_ih, b_hh, xproj);

  // 2) recurrence (persistent cooperative)
  void* args[] = {(void*)&xproj, (void*)&W_hh, (void*)&states, (void*)&h_buf,
                  (void*)&bar};
  hipLaunchCooperativeKernel(lstm_persistent, dim3(NBLOCKS), dim3(NTHREADS), args, 0, stream);

  // 3) attention scores + 4) softmax/pool/decode
  attn_gemm<<<dim3(250, 4), 256, 0, stream>>>(states, W_word, b_word, w_proj, part);
  softmax_pool_decode<<<64, 256, 0, stream>>>(part, states, dec_W, dec_b, out);
}